// Round 6
// baseline (202.283 us; speedup 1.0000x reference)
//
#include <hip/hip_runtime.h>

#define BATCH   8192
#define FEAT    256
#define NCLASS  100000
#define EPS_C   1e-6f

#define NC_ELEMS (NCLASS * FEAT)          // 25,600,000
#define NVEC (NC_ELEMS / 4)               // 6,400,000 float4s
#define FUSED_BLOCKS (NVEC / 256)         // 25,000 blocks; 4 rows (waves) each

typedef float f4 __attribute__((ext_vector_type(4)));

// Tiny: build per-class linked lists. head memset to -1 beforehand.
__global__ void build_kernel(const int* __restrict__ target,
                             int* __restrict__ head,
                             int* __restrict__ next) {
    int b = blockIdx.x * blockDim.x + threadIdx.x;
    if (b < BATCH) next[b] = atomicExch(&head[target[b]], b);
}

// One wave per center row. Untouched row: streamed copy. Touched row: walk
// the class list in-registers, produce updated row + per-sample loss
// partials. The +1-float output shift is handled per-wave via __shfl_up;
// each wave's lane 0 recomputes the single boundary element (last element
// of the previous row). No LDS, no __syncthreads, no atomics, no fences.
// Bulk streams use nontemporal load/store (read-once / write-once).
__global__ void fused_kernel(const float* __restrict__ centers,
                             const float* __restrict__ features,
                             const int* __restrict__ head,
                             const int* __restrict__ next,
                             float* __restrict__ partials,
                             float* __restrict__ out /* d_out base */) {
    int w = threadIdx.x >> 6;             // wave 0..3
    int l = threadIdx.x & 63;             // lane
    int r = blockIdx.x * 4 + w;           // center row for this wave
    size_t v = (size_t)r * 64 + l;        // float4 index into centers / out

    f4 c4 = __builtin_nontemporal_load(&((const f4*)centers)[v]);
    f4 n4 = c4;
    int h = head[r];
    if (h != -1) {
        f4 sumf = {0.f, 0.f, 0.f, 0.f};
        int n = 0;
        for (int s = h; s != -1; s = next[s]) {
            f4 f4v = ((const f4*)features)[(size_t)s * 64 + l];
            sumf += f4v;
            f4 d = c4 - f4v;
            float sq = d[0]*d[0] + d[1]*d[1] + d[2]*d[2] + d[3]*d[3];
            #pragma unroll
            for (int off = 32; off > 0; off >>= 1) sq += __shfl_down(sq, off, 64);
            if (l == 0) partials[s] = sq;   // each sample is in exactly one list
            n++;
        }
        float nf = (float)n;
        float inv = 1.0f / (nf + EPS_C);
        // new = c - (n*c - sum_f)/(n+eps)
        n4 = c4 - (nf * c4 - sumf) * inv;
    }

    // shift by +1: out[4v] = nc[4v-1] comes from the previous lane's n4.w
    float prev = __shfl_up(n4[3], 1);
    if (l == 0) {
        float val = 0.0f;                 // r==0: out[0] is the loss slot (finalize overwrites)
        if (r > 0) {
            int rp = r - 1;
            float c = centers[(size_t)rp * FEAT + 255];
            val = c;
            int hp = head[rp];
            if (hp != -1) {
                float sf = 0.0f; int n = 0;
                for (int s = hp; s != -1; s = next[s]) {
                    sf += features[(size_t)s * FEAT + 255]; n++;
                }
                float nf = (float)n;
                val = c - (nf * c - sf) / (nf + EPS_C);
            }
        }
        prev = val;
    }
    f4 ov = {prev, n4[0], n4[1], n4[2]};
    __builtin_nontemporal_store(ov, &((f4*)out)[v]);

    // tail element: out[NC_ELEMS] = new_centers[NC_ELEMS-1]
    if (r == NCLASS - 1 && l == 63) out[NC_ELEMS] = n4[3];
}

__global__ void finalize_kernel(const float* __restrict__ partials,
                                float* __restrict__ out0) {
    float s = 0.0f;
    for (int i = threadIdx.x; i < BATCH; i += 256) s += partials[i];
    #pragma unroll
    for (int off = 32; off > 0; off >>= 1) s += __shfl_down(s, off, 64);
    __shared__ float red[4];
    int wave = threadIdx.x >> 6;
    int lane = threadIdx.x & 63;
    if (lane == 0) red[wave] = s;
    __syncthreads();
    if (threadIdx.x == 0) {
        out0[0] = (red[0] + red[1] + red[2] + red[3]) / (float)(BATCH * FEAT);
    }
}

extern "C" void kernel_launch(void* const* d_in, const int* in_sizes, int n_in,
                              void* d_out, int out_size, void* d_ws, size_t ws_size,
                              hipStream_t stream) {
    const float* features = (const float*)d_in[0];
    const int*   target   = (const int*)d_in[1];
    const float* centers  = (const float*)d_in[2];
    float* out = (float*)d_out;

    int*   head     = (int*)d_ws;                                  // 100000 ints
    int*   next     = head + NCLASS;                               // 8192 ints
    float* partials = (float*)(next + BATCH);                      // 8192 floats

    hipMemsetAsync(head, 0xFF, NCLASS * sizeof(int), stream);      // head = -1
    build_kernel<<<(BATCH + 255) / 256, 256, 0, stream>>>(target, head, next);
    fused_kernel<<<FUSED_BLOCKS, 256, 0, stream>>>(centers, features, head, next,
                                                   partials, out);
    finalize_kernel<<<1, 256, 0, stream>>>(partials, out);
}

// Round 7
// 198.421 us; speedup vs baseline: 1.0195x; 1.0195x over previous
//
#include <hip/hip_runtime.h>

#define BATCH   8192
#define FEAT    256
#define NCLASS  100000
#define EPS_C   1e-6f

#define NC_ELEMS (NCLASS * FEAT)          // 25,600,000
#define NVEC (NC_ELEMS / 4)               // 6,400,000 float4s
#define FUSED_BLOCKS (NVEC / 256)         // 25,000 blocks; each covers 4 rows

typedef float f4 __attribute__((ext_vector_type(4)));

// Tiny: build per-class linked lists. head memset to -1 beforehand.
__global__ void build_kernel(const int* __restrict__ target,
                             int* __restrict__ head,
                             int* __restrict__ next) {
    int b = blockIdx.x * blockDim.x + threadIdx.x;
    if (b < BATCH) next[b] = atomicExch(&head[target[b]], b);
}

// One wave per center row (4 rows / 256-thread block).
// Untouched row: plain copy. Touched row: walk the class list, compute
// updated row + per-sample loss partials. Output is shifted +1 float
// (d_out[0] = loss slot) via an LDS staging buffer; the one cross-block
// boundary element is recomputed by thread 0 (per-BLOCK — R6's per-wave
// variant put the divergent walk on every wave's critical path, -6us).
// Bulk output store is nontemporal (write-once); centers loads stay cached
// so the boundary recompute hits L2.
__global__ void fused_kernel(const float* __restrict__ centers,
                             const float* __restrict__ features,
                             const int* __restrict__ head,
                             const int* __restrict__ next,
                             float* __restrict__ partials,
                             float* __restrict__ out /* d_out base */) {
    __shared__ float lds[1025];           // [0] = boundary elem, [1..1024] = block's rows
    int w = threadIdx.x >> 6;             // wave 0..3
    int l = threadIdx.x & 63;             // lane
    int r = blockIdx.x * 4 + w;           // center row for this wave

    f4 c4 = ((const f4*)(centers + (size_t)r * FEAT))[l];
    f4 n4 = c4;
    int h = head[r];
    if (h != -1) {
        f4 sumf = {0.f, 0.f, 0.f, 0.f};
        int n = 0;
        for (int s = h; s != -1; s = next[s]) {
            f4 f4v = ((const f4*)(features + (size_t)s * FEAT))[l];
            sumf += f4v;
            f4 d = c4 - f4v;
            float sq = d[0]*d[0] + d[1]*d[1] + d[2]*d[2] + d[3]*d[3];
            #pragma unroll
            for (int off = 32; off > 0; off >>= 1) sq += __shfl_down(sq, off, 64);
            if (l == 0) partials[s] = sq;   // each sample is in exactly one list
            n++;
        }
        float nf = (float)n;
        float inv = 1.0f / (nf + EPS_C);
        // new = c - (n*c - sum_f)/(n+eps)
        n4 = c4 - (nf * c4 - sumf) * inv;
    }

    // stage shifted by +1 into LDS
    int base = 1 + w * 256 + 4 * l;
    lds[base + 0] = n4[0]; lds[base + 1] = n4[1];
    lds[base + 2] = n4[2]; lds[base + 3] = n4[3];

    // boundary element: new_centers[block_base - 1] (last elem of prev row)
    if (threadIdx.x == 0) {
        float val = 0.0f;                 // block 0: out[0] is loss slot (finalize overwrites)
        if (blockIdx.x > 0) {
            int rp = blockIdx.x * 4 - 1;
            float c = centers[(size_t)rp * FEAT + 255];
            val = c;
            int hp = head[rp];
            if (hp != -1) {
                float sf = 0.0f; int n = 0;
                for (int s = hp; s != -1; s = next[s]) {
                    sf += features[(size_t)s * FEAT + 255]; n++;
                }
                float nf = (float)n;
                val = c - (nf * c - sf) / (nf + EPS_C);
            }
        }
        lds[0] = val;
    }
    // tail element: out[NC_ELEMS] = new_centers[NC_ELEMS-1]
    if (blockIdx.x == FUSED_BLOCKS - 1 && threadIdx.x == 255) {
        out[NC_ELEMS] = n4[3];
    }

    __syncthreads();

    int t = threadIdx.x;
    f4 ov = {lds[4*t + 0], lds[4*t + 1], lds[4*t + 2], lds[4*t + 3]};
    __builtin_nontemporal_store(ov, &((f4*)out)[(size_t)blockIdx.x * 256 + t]);
}

__global__ void finalize_kernel(const float* __restrict__ partials,
                                float* __restrict__ out0) {
    float s = 0.0f;
    for (int i = threadIdx.x; i < BATCH; i += 256) s += partials[i];
    #pragma unroll
    for (int off = 32; off > 0; off >>= 1) s += __shfl_down(s, off, 64);
    __shared__ float red[4];
    int wave = threadIdx.x >> 6;
    int lane = threadIdx.x & 63;
    if (lane == 0) red[wave] = s;
    __syncthreads();
    if (threadIdx.x == 0) {
        out0[0] = (red[0] + red[1] + red[2] + red[3]) / (float)(BATCH * FEAT);
    }
}

extern "C" void kernel_launch(void* const* d_in, const int* in_sizes, int n_in,
                              void* d_out, int out_size, void* d_ws, size_t ws_size,
                              hipStream_t stream) {
    const float* features = (const float*)d_in[0];
    const int*   target   = (const int*)d_in[1];
    const float* centers  = (const float*)d_in[2];
    float* out = (float*)d_out;

    int*   head     = (int*)d_ws;                                  // 100000 ints
    int*   next     = head + NCLASS;                               // 8192 ints
    float* partials = (float*)(next + BATCH);                      // 8192 floats

    hipMemsetAsync(head, 0xFF, NCLASS * sizeof(int), stream);      // head = -1
    build_kernel<<<(BATCH + 255) / 256, 256, 0, stream>>>(target, head, next);
    fused_kernel<<<FUSED_BLOCKS, 256, 0, stream>>>(centers, features, head, next,
                                                   partials, out);
    finalize_kernel<<<1, 256, 0, stream>>>(partials, out);
}